// Round 9
// baseline (602.173 us; speedup 1.0000x reference)
//
#include <hip/hip_runtime.h>
#include <math.h>

// ============ two-level counting sort + CSR gather (R8 lineage) ============
// R8 = 542us. Top dispatch k_gather_l2out 105us: latency-bound (HBM 17%, VALU 35%,
// occ 76%) on 2 serial roundtrips x 8 iters per node-wave. R9: gathers remapped to
// 8 slots x 8 lanes x float2 (4 iters) + 2-deep prefetch of sorted[]; bucket sort
// now single-pass into padded regions via global cursors (deletes bcount/bprefix).
#define BS   128          // nodes per bucket
#define BSL  7
#define NBLK 1024         // edge-chunk blocks for scatter
#define CAP  4608         // padded bucket capacity (mean 4096, +8 sigma)
#define CSTR 16           // cursor stride in u32 (64B padding, no line sharing)

typedef unsigned int uint;

// ---- init global bucket cursors to region bases ----
__global__ void k_init(uint* __restrict__ gcur, int NB) {
    int i = blockIdx.x * blockDim.x + threadIdx.x;
    if (i < NB) gcur[i * CSTR] = (uint)(i * CAP);
}

// ---- single-pass scatter into padded bucket regions; entry=(row<<7|col_local, w) ----
__global__ __launch_bounds__(256) void k_bscatter(const int* __restrict__ row,
        const int* __restrict__ col, const float* __restrict__ w,
        uint* __restrict__ gcur, int2* __restrict__ bsp, int E, int chunk) {
    int e0 = blockIdx.x * chunk, e1 = min(E, e0 + chunk);
    for (int e = e0 + threadIdx.x * 4; e < e1; e += 1024) {
        int4 c4, r4;
        float4 w4;
        if (e + 3 < e1) {
            c4 = *(const int4*)(col + e);
            r4 = *(const int4*)(row + e);
            w4 = *(const float4*)(w + e);
        } else {
            c4.x = col[e]; r4.x = row[e]; w4.x = w[e];
            c4.y = (e + 1 < e1) ? col[e + 1] : -1; r4.y = (e + 1 < e1) ? row[e + 1] : 0;
            w4.y = (e + 1 < e1) ? w[e + 1] : 0.f;
            c4.z = (e + 2 < e1) ? col[e + 2] : -1; r4.z = (e + 2 < e1) ? row[e + 2] : 0;
            w4.z = (e + 2 < e1) ? w[e + 2] : 0.f;
            c4.w = -1; r4.w = 0; w4.w = 0.f;
        }
        int cc[4] = {c4.x, c4.y, c4.z, c4.w};
        int rr[4] = {r4.x, r4.y, r4.z, r4.w};
        float ww[4] = {w4.x, w4.y, w4.z, w4.w};
#pragma unroll
        for (int k = 0; k < 4; k++) {
            if (cc[k] >= 0) {
                int bk = cc[k] >> BSL;
                uint slot = atomicAdd(&gcur[bk * CSTR], 1u);
                if (slot < (uint)((bk + 1) * CAP))
                    bsp[slot] = make_int2((rr[k] << BSL) | (cc[k] & (BS - 1)),
                                          __float_as_int(ww[k]));
            }
        }
    }
}

// ---- exclusive scan of bucket counts (from cursors) -> bbase[0..NB] ----
__global__ __launch_bounds__(256) void k_scanB(const uint* __restrict__ gcur,
                                               uint* __restrict__ bbase, int NB) {
    __shared__ uint s[256];
    __shared__ uint carry;
    int t = threadIdx.x;
    if (t == 0) carry = 0;
    __syncthreads();
    for (int base = 0; base < NB; base += 256) {
        int i = base + t;
        uint v = (i < NB) ? (gcur[i * CSTR] - (uint)(i * CAP)) : 0u;
        s[t] = v;
        __syncthreads();
        for (int off = 1; off < 256; off <<= 1) {
            uint x = (t >= off) ? s[t - off] : 0u;
            __syncthreads();
            s[t] += x;
            __syncthreads();
        }
        uint c = carry;
        if (i < NB) bbase[i] = c + s[t] - v;
        __syncthreads();
        if (t == 255) carry = c + s[255];
        __syncthreads();
    }
    if (t == 0) bbase[NB] = carry;
}

// ---- fine sort within bucket: padded -> dense; fuses dv + per-node CSR offsets ----
__global__ __launch_bounds__(256) void k_fsort(const int2* __restrict__ bsp,
        const uint* __restrict__ gcur, const uint* __restrict__ bbase,
        int2* __restrict__ fsorted, uint* __restrict__ nodeoff,
        float* __restrict__ dv, int N) {
    __shared__ uint hist[BS];
    __shared__ float wa[BS];
    __shared__ uint cur[BS];
    int b = blockIdx.x, t = threadIdx.x;
    if (t < BS) { hist[t] = 0u; wa[t] = 0.f; }
    __syncthreads();
    uint p0 = (uint)b * CAP;
    uint cnt = min(gcur[b * CSTR] - p0, (uint)CAP);
    uint out0 = bbase[b];
    for (uint k = t; k < cnt; k += 256) {
        int2 v = bsp[p0 + k];
        int lo = v.x & (BS - 1);
        atomicAdd(&hist[lo], 1u);
        atomicAdd(&wa[lo], __int_as_float(v.y));
    }
    __syncthreads();
    uint vv = (t < BS) ? hist[t] : 0u;          // Hillis-Steele over 128
    for (int off = 1; off < BS; off <<= 1) {
        uint x = (t < BS && t >= off) ? hist[t - off] : 0u;
        __syncthreads();
        if (t < BS) hist[t] += x;
        __syncthreads();
    }
    if (t < BS) {
        uint base = out0 + (hist[t] - vv);      // exclusive prefix
        cur[t] = base;
        nodeoff[(b << BSL) + t] = base;
        int n = (b << BSL) + t;
        if (n < N) dv[n] = rsqrtf(1.f + wa[t]); // self-loop weight 1
    }
    __syncthreads();
    for (uint k = t; k < cnt; k += 256) {
        int2 v = bsp[p0 + k];
        int lo = v.x & (BS - 1);
        uint slot = atomicAdd(&cur[lo], 1u);
        fsorted[slot] = make_int2(((uint)v.x) >> BSL, v.y);   // plain row
    }
}

// ---------------- x @ W1  (N x 256 @ 256 x 16), proven R4 version ----------------
__global__ __launch_bounds__(256) void k_xw1(const float* __restrict__ x,
                                             const float* __restrict__ W1,
                                             float* __restrict__ h, int N) {
    __shared__ float wsh[256 * 16];        // W1, then reused as reduction buffer
    int t = threadIdx.x;
    const float4* w4 = (const float4*)W1;
    float4* wsh4 = (float4*)wsh;
#pragma unroll
    for (int i = 0; i < 4; i++) wsh4[t + i * 256] = w4[t + i * 256];

    int lane = t & 63, kq = t >> 6;
    int r = blockIdx.x * 64 + lane;
    float acc[16];
#pragma unroll
    for (int j = 0; j < 16; j++) acc[j] = 0.f;
    __syncthreads();

    if (r < N) {
        const float4* xr = (const float4*)(x + (size_t)r * 256 + kq * 64);
#pragma unroll 4
        for (int k4 = 0; k4 < 16; k4++) {
            float4 xv = xr[k4];
            int kb = (kq * 64 + k4 * 4) * 16;
#pragma unroll
            for (int kk = 0; kk < 4; kk++) {
                float xs = (&xv.x)[kk];
                const float4* wrow = (const float4*)&wsh[kb + kk * 16];
#pragma unroll
                for (int jq = 0; jq < 4; jq++) {
                    float4 wv = wrow[jq];
                    acc[jq * 4 + 0] = fmaf(xs, wv.x, acc[jq * 4 + 0]);
                    acc[jq * 4 + 1] = fmaf(xs, wv.y, acc[jq * 4 + 1]);
                    acc[jq * 4 + 2] = fmaf(xs, wv.z, acc[jq * 4 + 2]);
                    acc[jq * 4 + 3] = fmaf(xs, wv.w, acc[jq * 4 + 3]);
                }
            }
        }
    }
    __syncthreads();
    if (kq) {
#pragma unroll
        for (int j = 0; j < 16; j++) wsh[((kq - 1) * 64 + lane) * 17 + j] = acc[j];
    }
    __syncthreads();
    if (kq == 0 && r < N) {
#pragma unroll
        for (int j = 0; j < 16; j++)
            acc[j] += wsh[lane * 17 + j] + wsh[(64 + lane) * 17 + j]
                    + wsh[(128 + lane) * 17 + j];
        float4* ho = (float4*)(h + (size_t)r * 16);
#pragma unroll
        for (int jq = 0; jq < 4; jq++)
            ho[jq] = make_float4(acc[jq * 4], acc[jq * 4 + 1],
                                 acc[jq * 4 + 2], acc[jq * 4 + 3]);
    }
}

// ---- layer1: wave per node; 8 slots x 8 lanes x float2; 2-deep prefetch ----
__global__ __launch_bounds__(256) void k_gather_l1(const int2* __restrict__ sorted,
        const uint* __restrict__ no, const float* __restrict__ dv,
        const float* __restrict__ h, const float* __restrict__ b1,
        float* __restrict__ ho, int N) {
    int wave = threadIdx.x >> 6;
    int node = blockIdx.x * 4 + wave;
    if (node >= N) return;
    int lane = threadIdx.x & 63;
    int slot = lane >> 3, fl = lane & 7;
    uint s0 = no[node], s1 = no[node + 1];
    float dvn = dv[node];
    float2 acc = make_float2(0.f, 0.f);
    uint k = s0 + slot;
    int2 pr = (k < s1) ? sorted[k] : make_int2(0, 0);   // w=0 for dummy
    int nit = (int)((s1 - s0 + 7) >> 3);
    for (int it = 0; it < nit; ++it) {
        uint kn = k + 8;
        int2 prn = (kn < s1) ? sorted[kn] : make_int2(0, 0);
        float nr = dv[pr.x] * __int_as_float(pr.y) * dvn;
        float2 hv = *(const float2*)(h + (size_t)pr.x * 16 + fl * 2);
        acc.x = fmaf(nr, hv.x, acc.x);
        acc.y = fmaf(nr, hv.y, acc.y);
        pr = prn; k = kn;
    }
#pragma unroll
    for (int off = 8; off < 64; off <<= 1) {
        acc.x += __shfl_xor(acc.x, off);
        acc.y += __shfl_xor(acc.y, off);
    }
    if (slot == 0) {
        float2 hs = *(const float2*)(h + (size_t)node * 16 + fl * 2);
        float2 bb = *(const float2*)(b1 + fl * 2);
        float2 r;
        r.x = fmaxf(acc.x + dvn * dvn * hs.x + bb.x, 0.f);
        r.y = fmaxf(acc.y + dvn * dvn * hs.y + bb.y, 0.f);
        *(float2*)(ho + (size_t)node * 16 + fl * 2) = r;
    }
}

// ---- layer2: same gather + fused @W2 + b2 + log_softmax ----
__global__ __launch_bounds__(256) void k_gather_l2out(const int2* __restrict__ sorted,
        const uint* __restrict__ no, const float* __restrict__ dv,
        const float* __restrict__ h, const float* __restrict__ W2,
        const float* __restrict__ b2, float* __restrict__ out, int N) {
    int wave = threadIdx.x >> 6;
    int node = blockIdx.x * 4 + wave;
    if (node >= N) return;
    int lane = threadIdx.x & 63;
    int slot = lane >> 3, fl = lane & 7;
    uint s0 = no[node], s1 = no[node + 1];
    float dvn = dv[node];
    float2 acc = make_float2(0.f, 0.f);
    uint k = s0 + slot;
    int2 pr = (k < s1) ? sorted[k] : make_int2(0, 0);
    int nit = (int)((s1 - s0 + 7) >> 3);
    for (int it = 0; it < nit; ++it) {
        uint kn = k + 8;
        int2 prn = (kn < s1) ? sorted[kn] : make_int2(0, 0);
        float nr = dv[pr.x] * __int_as_float(pr.y) * dvn;
        float2 hv = *(const float2*)(h + (size_t)pr.x * 16 + fl * 2);
        acc.x = fmaf(nr, hv.x, acc.x);
        acc.y = fmaf(nr, hv.y, acc.y);
        pr = prn; k = kn;
    }
#pragma unroll
    for (int off = 8; off < 64; off <<= 1) {
        acc.x += __shfl_xor(acc.x, off);
        acc.y += __shfl_xor(acc.y, off);
    }
    if (slot == 0) {                                   // add self-loop term
        float2 hs = *(const float2*)(h + (size_t)node * 16 + fl * 2);
        acc.x += dvn * dvn * hs.x;
        acc.y += dvn * dvn * hs.y;
    }
    float aj[16];
#pragma unroll
    for (int q = 0; q < 8; q++) {
        aj[2 * q]     = __shfl(acc.x, q);              // from lanes 0..7
        aj[2 * q + 1] = __shfl(acc.y, q);
    }
    float logit = -INFINITY;
    if (lane < 40) {
        logit = b2[lane];
#pragma unroll
        for (int q = 0; q < 16; q++) logit += aj[q] * W2[q * 40 + lane];
    }
    float m = logit;
#pragma unroll
    for (int off = 32; off; off >>= 1) m = fmaxf(m, __shfl_xor(m, off));
    float ex = (lane < 40) ? expf(logit - m) : 0.f;
    float ssum = ex;
#pragma unroll
    for (int off = 32; off; off >>= 1) ssum += __shfl_xor(ssum, off);
    if (lane < 40) out[(size_t)node * 40 + lane] = logit - m - logf(ssum);
}

extern "C" void kernel_launch(void* const* d_in, const int* in_sizes, int n_in,
                              void* d_out, int out_size, void* d_ws, size_t ws_size,
                              hipStream_t stream) {
    const float* x  = (const float*)d_in[0];
    const int*   ei = (const int*)d_in[1];
    const float* ew = (const float*)d_in[2];
    const float* W1 = (const float*)d_in[3];
    const float* b1 = (const float*)d_in[4];
    const float* W2 = (const float*)d_in[5];
    const float* b2 = (const float*)d_in[6];
    float* out = (float*)d_out;

    int N = in_sizes[0] / 256;
    int E = in_sizes[2];
    const int* row = ei;
    const int* col = ei + E;

    int NB = (N + BS - 1) >> BSL;                 // 782 buckets
    int chunk = (((E + NBLK - 1) / NBLK) + 3) & ~3;

    // workspace (u32 units), peak ~55.5MB:
    //   fsorted 2E (25.6MB) | bsorted_pad 2*NB*CAP (28.8MB, dead after fsort ->
    //   reused for h, h1 = 12.8MB) | gcur NB*CSTR | bbase NB+1 | nodeoff NB*BS+1 | dv N
    uint* ws32 = (uint*)d_ws;
    int2* fsorted = (int2*)ws32;
    int2* bsp     = (int2*)(ws32 + 2 * (size_t)E);
    uint* gcur    = ws32 + 2 * (size_t)E + 2 * (size_t)NB * CAP;
    uint* bbase   = gcur + (size_t)NB * CSTR;
    uint* nodeoff = bbase + NB + 1;
    float* dv     = (float*)(nodeoff + (size_t)NB * BS + 1);
    float* h      = (float*)bsp;                  // reuse after k_fsort
    float* h1     = h + (size_t)N * 16;

    k_init    <<<(NB + 255) / 256, 256, 0, stream>>>(gcur, NB);
    k_bscatter<<<NBLK, 256, 0, stream>>>(row, col, ew, gcur, bsp, E, chunk);
    k_scanB   <<<1, 256, 0, stream>>>(gcur, bbase, NB);
    k_fsort   <<<NB, 256, 0, stream>>>(bsp, gcur, bbase, fsorted, nodeoff, dv, N);
    k_xw1     <<<(N + 63) / 64, 256, 0, stream>>>(x, W1, h, N);
    k_gather_l1   <<<(N + 3) / 4, 256, 0, stream>>>(fsorted, nodeoff, dv, h, b1, h1, N);
    k_gather_l2out<<<(N + 3) / 4, 256, 0, stream>>>(fsorted, nodeoff, dv, h1, W2, b2, out, N);
}

// Round 10
// 472.333 us; speedup vs baseline: 1.2749x; 1.2749x over previous
//
#include <hip/hip_runtime.h>
#include <math.h>

// ============ two-level counting sort (R8 proven) + R9 gathers ============
// R9 lesson: global-cursor single-pass bscatter = 7x write amp (178MB, 200us) --
// interleaved slots from different XCDs never merge. R8's two-pass scheme gives
// each block a CONTIGUOUS sub-range per bucket (runs of ~4 int2) -> dense writes.
// This round: R8 sort kernels verbatim + R9's 8-slot x 8-lane x float2 gathers.
#define BS   128          // nodes per bucket
#define BSL  7
#define NBLK 1024         // edge-chunk blocks for count/scatter

typedef unsigned int uint;

// ---- pass 1: per-block histogram of bucket ids ----
__global__ __launch_bounds__(256) void k_bcount(const int* __restrict__ col,
                                                uint* __restrict__ cnt,
                                                int E, int NB, int chunk) {
    __shared__ uint bins[1024];
    for (int i = threadIdx.x; i < NB; i += 256) bins[i] = 0u;
    __syncthreads();
    int e0 = blockIdx.x * chunk, e1 = min(E, e0 + chunk);
    for (int e = e0 + threadIdx.x * 4; e < e1; e += 1024) {
        int4 c4;
        if (e + 3 < e1) c4 = *(const int4*)(col + e);
        else {
            c4.x = col[e];
            c4.y = (e + 1 < e1) ? col[e + 1] : -1;
            c4.z = (e + 2 < e1) ? col[e + 2] : -1;
            c4.w = (e + 3 < e1) ? col[e + 3] : -1;
        }
        if (c4.x >= 0) atomicAdd(&bins[c4.x >> BSL], 1u);
        if (c4.y >= 0) atomicAdd(&bins[c4.y >> BSL], 1u);
        if (c4.z >= 0) atomicAdd(&bins[c4.z >> BSL], 1u);
        if (c4.w >= 0) atomicAdd(&bins[c4.w >> BSL], 1u);
    }
    __syncthreads();
    for (int i = threadIdx.x; i < NB; i += 256)
        cnt[(size_t)i * NBLK + blockIdx.x] = bins[i];
}

// ---- pass 2: per bucket, exclusive scan over its NBLK block-counts + total ----
__global__ __launch_bounds__(256) void k_bprefix(uint* __restrict__ cnt,
                                                 uint* __restrict__ tot) {
    __shared__ uint s[256];
    uint* q = cnt + (size_t)blockIdx.x * NBLK;
    int t = threadIdx.x;
    uint v0 = q[t * 4], v1 = q[t * 4 + 1], v2 = q[t * 4 + 2], v3 = q[t * 4 + 3];
    uint s4 = v0 + v1 + v2 + v3;
    s[t] = s4;
    __syncthreads();
    for (int off = 1; off < 256; off <<= 1) {
        uint x = (t >= off) ? s[t - off] : 0u;
        __syncthreads();
        s[t] += x;
        __syncthreads();
    }
    uint excl = s[t] - s4;
    q[t * 4] = excl; q[t * 4 + 1] = excl + v0;
    q[t * 4 + 2] = excl + v0 + v1; q[t * 4 + 3] = excl + v0 + v1 + v2;
    if (t == 255) tot[blockIdx.x] = s[255];
}

// ---- pass 3: exclusive scan of bucket totals -> bbase[0..NB], bbase[NB]=E ----
__global__ __launch_bounds__(256) void k_scanT(const uint* __restrict__ tot,
                                               uint* __restrict__ bbase, int NB) {
    __shared__ uint s[256];
    __shared__ uint carry;
    int t = threadIdx.x;
    if (t == 0) carry = 0;
    __syncthreads();
    for (int base = 0; base < NB; base += 256) {
        int i = base + t;
        uint v = (i < NB) ? tot[i] : 0u;
        s[t] = v;
        __syncthreads();
        for (int off = 1; off < 256; off <<= 1) {
            uint x = (t >= off) ? s[t - off] : 0u;
            __syncthreads();
            s[t] += x;
            __syncthreads();
        }
        uint c = carry;
        if (i < NB) bbase[i] = c + s[t] - v;
        __syncthreads();
        if (t == 255) carry = c + s[255];
        __syncthreads();
    }
    if (t == 0) bbase[NB] = carry;
}

// ---- pass 4: scatter edges to bucket order; entry=(row<<7|col_local, w) ----
__global__ __launch_bounds__(256) void k_bscatter(const int* __restrict__ row,
        const int* __restrict__ col, const float* __restrict__ w,
        const uint* __restrict__ cnt, const uint* __restrict__ bbase,
        int2* __restrict__ bsorted, int E, int NB, int chunk) {
    __shared__ uint cur[1024];
    for (int i = threadIdx.x; i < NB; i += 256)
        cur[i] = bbase[i] + cnt[(size_t)i * NBLK + blockIdx.x];
    __syncthreads();
    int e0 = blockIdx.x * chunk, e1 = min(E, e0 + chunk);
    for (int e = e0 + threadIdx.x * 4; e < e1; e += 1024) {
        int4 c4, r4;
        float4 w4;
        if (e + 3 < e1) {
            c4 = *(const int4*)(col + e);
            r4 = *(const int4*)(row + e);
            w4 = *(const float4*)(w + e);
        } else {
            c4.x = col[e]; r4.x = row[e]; w4.x = w[e];
            c4.y = (e + 1 < e1) ? col[e + 1] : -1; r4.y = (e + 1 < e1) ? row[e + 1] : 0;
            w4.y = (e + 1 < e1) ? w[e + 1] : 0.f;
            c4.z = (e + 2 < e1) ? col[e + 2] : -1; r4.z = (e + 2 < e1) ? row[e + 2] : 0;
            w4.z = (e + 2 < e1) ? w[e + 2] : 0.f;
            c4.w = -1; r4.w = 0; w4.w = 0.f;
        }
        int cc[4] = {c4.x, c4.y, c4.z, c4.w};
        int rr[4] = {r4.x, r4.y, r4.z, r4.w};
        float ww[4] = {w4.x, w4.y, w4.z, w4.w};
#pragma unroll
        for (int k = 0; k < 4; k++) {
            if (cc[k] >= 0) {
                uint slot = atomicAdd(&cur[cc[k] >> BSL], 1u);
                bsorted[slot] = make_int2((rr[k] << BSL) | (cc[k] & (BS - 1)),
                                          __float_as_int(ww[k]));
            }
        }
    }
}

// ---- pass 5: fine sort within bucket; fuses dv + per-node CSR offsets ----
__global__ __launch_bounds__(256) void k_fsort(const int2* __restrict__ bsorted,
        const uint* __restrict__ bbase, int2* __restrict__ fsorted,
        uint* __restrict__ nodeoff, float* __restrict__ dv, int N) {
    __shared__ uint hist[BS];
    __shared__ float wa[BS];
    __shared__ uint cur[BS];
    int b = blockIdx.x, t = threadIdx.x;
    if (t < BS) { hist[t] = 0u; wa[t] = 0.f; }
    __syncthreads();
    uint s0 = bbase[b], s1 = bbase[b + 1];
    for (uint k = s0 + t; k < s1; k += 256) {
        int2 v = bsorted[k];
        int lo = v.x & (BS - 1);
        atomicAdd(&hist[lo], 1u);
        atomicAdd(&wa[lo], __int_as_float(v.y));
    }
    __syncthreads();
    uint vv = (t < BS) ? hist[t] : 0u;          // Hillis-Steele over 128
    for (int off = 1; off < BS; off <<= 1) {
        uint x = (t < BS && t >= off) ? hist[t - off] : 0u;
        __syncthreads();
        if (t < BS) hist[t] += x;
        __syncthreads();
    }
    if (t < BS) {
        uint base = s0 + (hist[t] - vv);        // exclusive prefix
        cur[t] = base;
        nodeoff[(b << BSL) + t] = base;
        int n = (b << BSL) + t;
        if (n < N) dv[n] = rsqrtf(1.f + wa[t]); // self-loop weight 1
    }
    __syncthreads();
    for (uint k = s0 + t; k < s1; k += 256) {
        int2 v = bsorted[k];
        int lo = v.x & (BS - 1);
        uint slot = atomicAdd(&cur[lo], 1u);
        fsorted[slot] = make_int2(((uint)v.x) >> BSL, v.y);   // plain row
    }
}

// ---------------- x @ W1  (N x 256 @ 256 x 16), proven R4 version ----------------
__global__ __launch_bounds__(256) void k_xw1(const float* __restrict__ x,
                                             const float* __restrict__ W1,
                                             float* __restrict__ h, int N) {
    __shared__ float wsh[256 * 16];        // W1, then reused as reduction buffer
    int t = threadIdx.x;
    const float4* w4 = (const float4*)W1;
    float4* wsh4 = (float4*)wsh;
#pragma unroll
    for (int i = 0; i < 4; i++) wsh4[t + i * 256] = w4[t + i * 256];

    int lane = t & 63, kq = t >> 6;
    int r = blockIdx.x * 64 + lane;
    float acc[16];
#pragma unroll
    for (int j = 0; j < 16; j++) acc[j] = 0.f;
    __syncthreads();

    if (r < N) {
        const float4* xr = (const float4*)(x + (size_t)r * 256 + kq * 64);
#pragma unroll 4
        for (int k4 = 0; k4 < 16; k4++) {
            float4 xv = xr[k4];
            int kb = (kq * 64 + k4 * 4) * 16;
#pragma unroll
            for (int kk = 0; kk < 4; kk++) {
                float xs = (&xv.x)[kk];
                const float4* wrow = (const float4*)&wsh[kb + kk * 16];
#pragma unroll
                for (int jq = 0; jq < 4; jq++) {
                    float4 wv = wrow[jq];
                    acc[jq * 4 + 0] = fmaf(xs, wv.x, acc[jq * 4 + 0]);
                    acc[jq * 4 + 1] = fmaf(xs, wv.y, acc[jq * 4 + 1]);
                    acc[jq * 4 + 2] = fmaf(xs, wv.z, acc[jq * 4 + 2]);
                    acc[jq * 4 + 3] = fmaf(xs, wv.w, acc[jq * 4 + 3]);
                }
            }
        }
    }
    __syncthreads();
    if (kq) {
#pragma unroll
        for (int j = 0; j < 16; j++) wsh[((kq - 1) * 64 + lane) * 17 + j] = acc[j];
    }
    __syncthreads();
    if (kq == 0 && r < N) {
#pragma unroll
        for (int j = 0; j < 16; j++)
            acc[j] += wsh[lane * 17 + j] + wsh[(64 + lane) * 17 + j]
                    + wsh[(128 + lane) * 17 + j];
        float4* ho = (float4*)(h + (size_t)r * 16);
#pragma unroll
        for (int jq = 0; jq < 4; jq++)
            ho[jq] = make_float4(acc[jq * 4], acc[jq * 4 + 1],
                                 acc[jq * 4 + 2], acc[jq * 4 + 3]);
    }
}

// ---- layer1: wave per node; 8 slots x 8 lanes x float2; 2-deep prefetch (R9) ----
__global__ __launch_bounds__(256) void k_gather_l1(const int2* __restrict__ sorted,
        const uint* __restrict__ no, const float* __restrict__ dv,
        const float* __restrict__ h, const float* __restrict__ b1,
        float* __restrict__ ho, int N) {
    int wave = threadIdx.x >> 6;
    int node = blockIdx.x * 4 + wave;
    if (node >= N) return;
    int lane = threadIdx.x & 63;
    int slot = lane >> 3, fl = lane & 7;
    uint s0 = no[node], s1 = no[node + 1];
    float dvn = dv[node];
    float2 acc = make_float2(0.f, 0.f);
    uint k = s0 + slot;
    int2 pr = (k < s1) ? sorted[k] : make_int2(0, 0);   // w=0 for dummy
    int nit = (int)((s1 - s0 + 7) >> 3);
    for (int it = 0; it < nit; ++it) {
        uint kn = k + 8;
        int2 prn = (kn < s1) ? sorted[kn] : make_int2(0, 0);
        float nr = dv[pr.x] * __int_as_float(pr.y) * dvn;
        float2 hv = *(const float2*)(h + (size_t)pr.x * 16 + fl * 2);
        acc.x = fmaf(nr, hv.x, acc.x);
        acc.y = fmaf(nr, hv.y, acc.y);
        pr = prn; k = kn;
    }
#pragma unroll
    for (int off = 8; off < 64; off <<= 1) {
        acc.x += __shfl_xor(acc.x, off);
        acc.y += __shfl_xor(acc.y, off);
    }
    if (slot == 0) {
        float2 hs = *(const float2*)(h + (size_t)node * 16 + fl * 2);
        float2 bb = *(const float2*)(b1 + fl * 2);
        float2 r;
        r.x = fmaxf(acc.x + dvn * dvn * hs.x + bb.x, 0.f);
        r.y = fmaxf(acc.y + dvn * dvn * hs.y + bb.y, 0.f);
        *(float2*)(ho + (size_t)node * 16 + fl * 2) = r;
    }
}

// ---- layer2: same gather + fused @W2 + b2 + log_softmax (R9) ----
__global__ __launch_bounds__(256) void k_gather_l2out(const int2* __restrict__ sorted,
        const uint* __restrict__ no, const float* __restrict__ dv,
        const float* __restrict__ h, const float* __restrict__ W2,
        const float* __restrict__ b2, float* __restrict__ out, int N) {
    int wave = threadIdx.x >> 6;
    int node = blockIdx.x * 4 + wave;
    if (node >= N) return;
    int lane = threadIdx.x & 63;
    int slot = lane >> 3, fl = lane & 7;
    uint s0 = no[node], s1 = no[node + 1];
    float dvn = dv[node];
    float2 acc = make_float2(0.f, 0.f);
    uint k = s0 + slot;
    int2 pr = (k < s1) ? sorted[k] : make_int2(0, 0);
    int nit = (int)((s1 - s0 + 7) >> 3);
    for (int it = 0; it < nit; ++it) {
        uint kn = k + 8;
        int2 prn = (kn < s1) ? sorted[kn] : make_int2(0, 0);
        float nr = dv[pr.x] * __int_as_float(pr.y) * dvn;
        float2 hv = *(const float2*)(h + (size_t)pr.x * 16 + fl * 2);
        acc.x = fmaf(nr, hv.x, acc.x);
        acc.y = fmaf(nr, hv.y, acc.y);
        pr = prn; k = kn;
    }
#pragma unroll
    for (int off = 8; off < 64; off <<= 1) {
        acc.x += __shfl_xor(acc.x, off);
        acc.y += __shfl_xor(acc.y, off);
    }
    if (slot == 0) {                                   // add self-loop term
        float2 hs = *(const float2*)(h + (size_t)node * 16 + fl * 2);
        acc.x += dvn * dvn * hs.x;
        acc.y += dvn * dvn * hs.y;
    }
    float aj[16];
#pragma unroll
    for (int q = 0; q < 8; q++) {
        aj[2 * q]     = __shfl(acc.x, q);              // from lanes 0..7
        aj[2 * q + 1] = __shfl(acc.y, q);
    }
    float logit = -INFINITY;
    if (lane < 40) {
        logit = b2[lane];
#pragma unroll
        for (int q = 0; q < 16; q++) logit += aj[q] * W2[q * 40 + lane];
    }
    float m = logit;
#pragma unroll
    for (int off = 32; off; off >>= 1) m = fmaxf(m, __shfl_xor(m, off));
    float ex = (lane < 40) ? expf(logit - m) : 0.f;
    float ssum = ex;
#pragma unroll
    for (int off = 32; off; off >>= 1) ssum += __shfl_xor(ssum, off);
    if (lane < 40) out[(size_t)node * 40 + lane] = logit - m - logf(ssum);
}

extern "C" void kernel_launch(void* const* d_in, const int* in_sizes, int n_in,
                              void* d_out, int out_size, void* d_ws, size_t ws_size,
                              hipStream_t stream) {
    const float* x  = (const float*)d_in[0];
    const int*   ei = (const int*)d_in[1];
    const float* ew = (const float*)d_in[2];
    const float* W1 = (const float*)d_in[3];
    const float* b1 = (const float*)d_in[4];
    const float* W2 = (const float*)d_in[5];
    const float* b2 = (const float*)d_in[6];
    float* out = (float*)d_out;

    int N = in_sizes[0] / 256;
    int E = in_sizes[2];
    const int* row = ei;
    const int* col = ei + E;

    int NB = (N + BS - 1) >> BSL;                 // 782 buckets
    int chunk = (((E + NBLK - 1) / NBLK) + 3) & ~3;

    // workspace (u32 units), peak ~55MB (R8 proven layout):
    //   fsorted 2E | bsorted 2E (dead after fsort -> reused for h, h1)
    //   | cnt NB*NBLK | tot NB | bbase NB+1 | nodeoff NB*BS+1 | dv N
    uint* ws32 = (uint*)d_ws;
    int2* fsorted = (int2*)ws32;
    int2* bsorted = (int2*)(ws32 + 2 * (size_t)E);
    uint* cnt     = ws32 + 4 * (size_t)E;
    uint* tot     = cnt + (size_t)NB * NBLK;
    uint* bbase   = tot + NB;
    uint* nodeoff = bbase + NB + 1;
    float* dv     = (float*)(nodeoff + (size_t)NB * BS + 1);
    float* h      = (float*)bsorted;              // reuse after k_fsort
    float* h1     = h + (size_t)N * 16;

    k_bcount  <<<NBLK, 256, 0, stream>>>(col, cnt, E, NB, chunk);
    k_bprefix <<<NB, 256, 0, stream>>>(cnt, tot);
    k_scanT   <<<1, 256, 0, stream>>>(tot, bbase, NB);
    k_bscatter<<<NBLK, 256, 0, stream>>>(row, col, ew, cnt, bbase, bsorted, E, NB, chunk);
    k_fsort   <<<NB, 256, 0, stream>>>(bsorted, bbase, fsorted, nodeoff, dv, N);
    k_xw1     <<<(N + 63) / 64, 256, 0, stream>>>(x, W1, h, N);
    k_gather_l1   <<<(N + 3) / 4, 256, 0, stream>>>(fsorted, nodeoff, dv, h, b1, h1, N);
    k_gather_l2out<<<(N + 3) / 4, 256, 0, stream>>>(fsorted, nodeoff, dv, h1, W2, b2, out, N);
}

// Round 11
// 418.152 us; speedup vs baseline: 1.4401x; 1.1296x over previous
//
#include <hip/hip_runtime.h>
#include <math.h>

// ============ two-level counting sort (R8 proven) + R9 gathers + coalesced xw1 ============
// R10 = 472us. Top: k_xw1 106us, FETCH 292MB vs 102.4MB ideal (2.85x over-fetch):
// per-lane-row loads put 64 lanes on 64 distinct lines (1024B stride) -> eviction
// before reuse. R11: quad-lane-per-row layout -> 16 fully-used 64B segments per
// wave-load (x fetched once); W1 in stride-28 LDS (16B-aligned, 2-way=free banks);
// quad shfl reduce (no LDS reduce buffer, no extra barriers).
#define BS   128          // nodes per bucket
#define BSL  7
#define NBLK 1024         // edge-chunk blocks for count/scatter

typedef unsigned int uint;

// ---- pass 1: per-block histogram of bucket ids ----
__global__ __launch_bounds__(256) void k_bcount(const int* __restrict__ col,
                                                uint* __restrict__ cnt,
                                                int E, int NB, int chunk) {
    __shared__ uint bins[1024];
    for (int i = threadIdx.x; i < NB; i += 256) bins[i] = 0u;
    __syncthreads();
    int e0 = blockIdx.x * chunk, e1 = min(E, e0 + chunk);
    for (int e = e0 + threadIdx.x * 4; e < e1; e += 1024) {
        int4 c4;
        if (e + 3 < e1) c4 = *(const int4*)(col + e);
        else {
            c4.x = col[e];
            c4.y = (e + 1 < e1) ? col[e + 1] : -1;
            c4.z = (e + 2 < e1) ? col[e + 2] : -1;
            c4.w = (e + 3 < e1) ? col[e + 3] : -1;
        }
        if (c4.x >= 0) atomicAdd(&bins[c4.x >> BSL], 1u);
        if (c4.y >= 0) atomicAdd(&bins[c4.y >> BSL], 1u);
        if (c4.z >= 0) atomicAdd(&bins[c4.z >> BSL], 1u);
        if (c4.w >= 0) atomicAdd(&bins[c4.w >> BSL], 1u);
    }
    __syncthreads();
    for (int i = threadIdx.x; i < NB; i += 256)
        cnt[(size_t)i * NBLK + blockIdx.x] = bins[i];
}

// ---- pass 2: per bucket, exclusive scan over its NBLK block-counts + total ----
__global__ __launch_bounds__(256) void k_bprefix(uint* __restrict__ cnt,
                                                 uint* __restrict__ tot) {
    __shared__ uint s[256];
    uint* q = cnt + (size_t)blockIdx.x * NBLK;
    int t = threadIdx.x;
    uint v0 = q[t * 4], v1 = q[t * 4 + 1], v2 = q[t * 4 + 2], v3 = q[t * 4 + 3];
    uint s4 = v0 + v1 + v2 + v3;
    s[t] = s4;
    __syncthreads();
    for (int off = 1; off < 256; off <<= 1) {
        uint x = (t >= off) ? s[t - off] : 0u;
        __syncthreads();
        s[t] += x;
        __syncthreads();
    }
    uint excl = s[t] - s4;
    q[t * 4] = excl; q[t * 4 + 1] = excl + v0;
    q[t * 4 + 2] = excl + v0 + v1; q[t * 4 + 3] = excl + v0 + v1 + v2;
    if (t == 255) tot[blockIdx.x] = s[255];
}

// ---- pass 3: exclusive scan of bucket totals -> bbase[0..NB], bbase[NB]=E ----
__global__ __launch_bounds__(256) void k_scanT(const uint* __restrict__ tot,
                                               uint* __restrict__ bbase, int NB) {
    __shared__ uint s[256];
    __shared__ uint carry;
    int t = threadIdx.x;
    if (t == 0) carry = 0;
    __syncthreads();
    for (int base = 0; base < NB; base += 256) {
        int i = base + t;
        uint v = (i < NB) ? tot[i] : 0u;
        s[t] = v;
        __syncthreads();
        for (int off = 1; off < 256; off <<= 1) {
            uint x = (t >= off) ? s[t - off] : 0u;
            __syncthreads();
            s[t] += x;
            __syncthreads();
        }
        uint c = carry;
        if (i < NB) bbase[i] = c + s[t] - v;
        __syncthreads();
        if (t == 255) carry = c + s[255];
        __syncthreads();
    }
    if (t == 0) bbase[NB] = carry;
}

// ---- pass 4: scatter edges to bucket order; entry=(row<<7|col_local, w) ----
__global__ __launch_bounds__(256) void k_bscatter(const int* __restrict__ row,
        const int* __restrict__ col, const float* __restrict__ w,
        const uint* __restrict__ cnt, const uint* __restrict__ bbase,
        int2* __restrict__ bsorted, int E, int NB, int chunk) {
    __shared__ uint cur[1024];
    for (int i = threadIdx.x; i < NB; i += 256)
        cur[i] = bbase[i] + cnt[(size_t)i * NBLK + blockIdx.x];
    __syncthreads();
    int e0 = blockIdx.x * chunk, e1 = min(E, e0 + chunk);
    for (int e = e0 + threadIdx.x * 4; e < e1; e += 1024) {
        int4 c4, r4;
        float4 w4;
        if (e + 3 < e1) {
            c4 = *(const int4*)(col + e);
            r4 = *(const int4*)(row + e);
            w4 = *(const float4*)(w + e);
        } else {
            c4.x = col[e]; r4.x = row[e]; w4.x = w[e];
            c4.y = (e + 1 < e1) ? col[e + 1] : -1; r4.y = (e + 1 < e1) ? row[e + 1] : 0;
            w4.y = (e + 1 < e1) ? w[e + 1] : 0.f;
            c4.z = (e + 2 < e1) ? col[e + 2] : -1; r4.z = (e + 2 < e1) ? row[e + 2] : 0;
            w4.z = (e + 2 < e1) ? w[e + 2] : 0.f;
            c4.w = -1; r4.w = 0; w4.w = 0.f;
        }
        int cc[4] = {c4.x, c4.y, c4.z, c4.w};
        int rr[4] = {r4.x, r4.y, r4.z, r4.w};
        float ww[4] = {w4.x, w4.y, w4.z, w4.w};
#pragma unroll
        for (int k = 0; k < 4; k++) {
            if (cc[k] >= 0) {
                uint slot = atomicAdd(&cur[cc[k] >> BSL], 1u);
                bsorted[slot] = make_int2((rr[k] << BSL) | (cc[k] & (BS - 1)),
                                          __float_as_int(ww[k]));
            }
        }
    }
}

// ---- pass 5: fine sort within bucket; fuses dv + per-node CSR offsets ----
__global__ __launch_bounds__(256) void k_fsort(const int2* __restrict__ bsorted,
        const uint* __restrict__ bbase, int2* __restrict__ fsorted,
        uint* __restrict__ nodeoff, float* __restrict__ dv, int N) {
    __shared__ uint hist[BS];
    __shared__ float wa[BS];
    __shared__ uint cur[BS];
    int b = blockIdx.x, t = threadIdx.x;
    if (t < BS) { hist[t] = 0u; wa[t] = 0.f; }
    __syncthreads();
    uint s0 = bbase[b], s1 = bbase[b + 1];
    for (uint k = s0 + t; k < s1; k += 256) {
        int2 v = bsorted[k];
        int lo = v.x & (BS - 1);
        atomicAdd(&hist[lo], 1u);
        atomicAdd(&wa[lo], __int_as_float(v.y));
    }
    __syncthreads();
    uint vv = (t < BS) ? hist[t] : 0u;          // Hillis-Steele over 128
    for (int off = 1; off < BS; off <<= 1) {
        uint x = (t < BS && t >= off) ? hist[t - off] : 0u;
        __syncthreads();
        if (t < BS) hist[t] += x;
        __syncthreads();
    }
    if (t < BS) {
        uint base = s0 + (hist[t] - vv);        // exclusive prefix
        cur[t] = base;
        nodeoff[(b << BSL) + t] = base;
        int n = (b << BSL) + t;
        if (n < N) dv[n] = rsqrtf(1.f + wa[t]); // self-loop weight 1
    }
    __syncthreads();
    for (uint k = s0 + t; k < s1; k += 256) {
        int2 v = bsorted[k];
        int lo = v.x & (BS - 1);
        uint slot = atomicAdd(&cur[lo], 1u);
        fsorted[slot] = make_int2(((uint)v.x) >> BSL, v.y);   // plain row
    }
}

// ---------------- x @ W1: coalesced quad-lane-per-row version ----------------
// lane l: row = l>>2, quad q = l&3 owns k-quarter (float4s q+4*k4). Lanes 0-3 read
// bytes +0/16/32/48 of one row -> 16 fully-used 64B segments per wave-load; x is
// fetched exactly once. W1 in LDS stride 28 (16B-aligned; quads hit banks
// {0,16,0,16} = 2-way = free). Quad shfl reduce; quad-lane 0 writes 64B.
#define WST 28
__global__ __launch_bounds__(256) void k_xw1(const float* __restrict__ x,
                                             const float* __restrict__ W1,
                                             float* __restrict__ h, int N) {
    __shared__ float wsh[256 * WST];
    int t = threadIdx.x;
    for (int i = t; i < 4096; i += 256)
        wsh[(i >> 4) * WST + (i & 15)] = W1[i];
    __syncthreads();

    int lane = t & 63, wv = t >> 6;
    int q = lane & 3;
    int r = blockIdx.x * 64 + wv * 16 + (lane >> 2);
    float acc[16];
#pragma unroll
    for (int j = 0; j < 16; j++) acc[j] = 0.f;

    if (r < N) {
        const float4* xr = (const float4*)(x + (size_t)r * 256);
#pragma unroll 4
        for (int k4 = 0; k4 < 16; k4++) {
            float4 xv = xr[q + k4 * 4];
            int kbase = (q + 4 * k4) * 4;
#pragma unroll
            for (int kk = 0; kk < 4; kk++) {
                float xs = (&xv.x)[kk];
                const float* wr = &wsh[(kbase + kk) * WST];
#pragma unroll
                for (int jq = 0; jq < 4; jq++) {
                    float4 wv4 = *(const float4*)(wr + jq * 4);
                    acc[jq * 4 + 0] = fmaf(xs, wv4.x, acc[jq * 4 + 0]);
                    acc[jq * 4 + 1] = fmaf(xs, wv4.y, acc[jq * 4 + 1]);
                    acc[jq * 4 + 2] = fmaf(xs, wv4.z, acc[jq * 4 + 2]);
                    acc[jq * 4 + 3] = fmaf(xs, wv4.w, acc[jq * 4 + 3]);
                }
            }
        }
    }
#pragma unroll
    for (int j = 0; j < 16; j++) {      // reduce across quad (unconditional)
        acc[j] += __shfl_xor(acc[j], 1);
        acc[j] += __shfl_xor(acc[j], 2);
    }
    if (q == 0 && r < N) {
        float4* ho = (float4*)(h + (size_t)r * 16);
#pragma unroll
        for (int jq = 0; jq < 4; jq++)
            ho[jq] = make_float4(acc[jq * 4], acc[jq * 4 + 1],
                                 acc[jq * 4 + 2], acc[jq * 4 + 3]);
    }
}

// ---- layer1: wave per node; 8 slots x 8 lanes x float2; 2-deep prefetch (R9) ----
__global__ __launch_bounds__(256) void k_gather_l1(const int2* __restrict__ sorted,
        const uint* __restrict__ no, const float* __restrict__ dv,
        const float* __restrict__ h, const float* __restrict__ b1,
        float* __restrict__ ho, int N) {
    int wave = threadIdx.x >> 6;
    int node = blockIdx.x * 4 + wave;
    if (node >= N) return;
    int lane = threadIdx.x & 63;
    int slot = lane >> 3, fl = lane & 7;
    uint s0 = no[node], s1 = no[node + 1];
    float dvn = dv[node];
    float2 acc = make_float2(0.f, 0.f);
    uint k = s0 + slot;
    int2 pr = (k < s1) ? sorted[k] : make_int2(0, 0);   // w=0 for dummy
    int nit = (int)((s1 - s0 + 7) >> 3);
    for (int it = 0; it < nit; ++it) {
        uint kn = k + 8;
        int2 prn = (kn < s1) ? sorted[kn] : make_int2(0, 0);
        float nr = dv[pr.x] * __int_as_float(pr.y) * dvn;
        float2 hv = *(const float2*)(h + (size_t)pr.x * 16 + fl * 2);
        acc.x = fmaf(nr, hv.x, acc.x);
        acc.y = fmaf(nr, hv.y, acc.y);
        pr = prn; k = kn;
    }
#pragma unroll
    for (int off = 8; off < 64; off <<= 1) {
        acc.x += __shfl_xor(acc.x, off);
        acc.y += __shfl_xor(acc.y, off);
    }
    if (slot == 0) {
        float2 hs = *(const float2*)(h + (size_t)node * 16 + fl * 2);
        float2 bb = *(const float2*)(b1 + fl * 2);
        float2 r;
        r.x = fmaxf(acc.x + dvn * dvn * hs.x + bb.x, 0.f);
        r.y = fmaxf(acc.y + dvn * dvn * hs.y + bb.y, 0.f);
        *(float2*)(ho + (size_t)node * 16 + fl * 2) = r;
    }
}

// ---- layer2: same gather + fused @W2 + b2 + log_softmax (R9) ----
__global__ __launch_bounds__(256) void k_gather_l2out(const int2* __restrict__ sorted,
        const uint* __restrict__ no, const float* __restrict__ dv,
        const float* __restrict__ h, const float* __restrict__ W2,
        const float* __restrict__ b2, float* __restrict__ out, int N) {
    int wave = threadIdx.x >> 6;
    int node = blockIdx.x * 4 + wave;
    if (node >= N) return;
    int lane = threadIdx.x & 63;
    int slot = lane >> 3, fl = lane & 7;
    uint s0 = no[node], s1 = no[node + 1];
    float dvn = dv[node];
    float2 acc = make_float2(0.f, 0.f);
    uint k = s0 + slot;
    int2 pr = (k < s1) ? sorted[k] : make_int2(0, 0);
    int nit = (int)((s1 - s0 + 7) >> 3);
    for (int it = 0; it < nit; ++it) {
        uint kn = k + 8;
        int2 prn = (kn < s1) ? sorted[kn] : make_int2(0, 0);
        float nr = dv[pr.x] * __int_as_float(pr.y) * dvn;
        float2 hv = *(const float2*)(h + (size_t)pr.x * 16 + fl * 2);
        acc.x = fmaf(nr, hv.x, acc.x);
        acc.y = fmaf(nr, hv.y, acc.y);
        pr = prn; k = kn;
    }
#pragma unroll
    for (int off = 8; off < 64; off <<= 1) {
        acc.x += __shfl_xor(acc.x, off);
        acc.y += __shfl_xor(acc.y, off);
    }
    if (slot == 0) {                                   // add self-loop term
        float2 hs = *(const float2*)(h + (size_t)node * 16 + fl * 2);
        acc.x += dvn * dvn * hs.x;
        acc.y += dvn * dvn * hs.y;
    }
    float aj[16];
#pragma unroll
    for (int q = 0; q < 8; q++) {
        aj[2 * q]     = __shfl(acc.x, q);              // from lanes 0..7
        aj[2 * q + 1] = __shfl(acc.y, q);
    }
    float logit = -INFINITY;
    if (lane < 40) {
        logit = b2[lane];
#pragma unroll
        for (int q = 0; q < 16; q++) logit += aj[q] * W2[q * 40 + lane];
    }
    float m = logit;
#pragma unroll
    for (int off = 32; off; off >>= 1) m = fmaxf(m, __shfl_xor(m, off));
    float ex = (lane < 40) ? expf(logit - m) : 0.f;
    float ssum = ex;
#pragma unroll
    for (int off = 32; off; off >>= 1) ssum += __shfl_xor(ssum, off);
    if (lane < 40) out[(size_t)node * 40 + lane] = logit - m - logf(ssum);
}

extern "C" void kernel_launch(void* const* d_in, const int* in_sizes, int n_in,
                              void* d_out, int out_size, void* d_ws, size_t ws_size,
                              hipStream_t stream) {
    const float* x  = (const float*)d_in[0];
    const int*   ei = (const int*)d_in[1];
    const float* ew = (const float*)d_in[2];
    const float* W1 = (const float*)d_in[3];
    const float* b1 = (const float*)d_in[4];
    const float* W2 = (const float*)d_in[5];
    const float* b2 = (const float*)d_in[6];
    float* out = (float*)d_out;

    int N = in_sizes[0] / 256;
    int E = in_sizes[2];
    const int* row = ei;
    const int* col = ei + E;

    int NB = (N + BS - 1) >> BSL;                 // 782 buckets
    int chunk = (((E + NBLK - 1) / NBLK) + 3) & ~3;

    // workspace (u32 units), peak ~55MB (R8 proven layout):
    //   fsorted 2E | bsorted 2E (dead after fsort -> reused for h, h1)
    //   | cnt NB*NBLK | tot NB | bbase NB+1 | nodeoff NB*BS+1 | dv N
    uint* ws32 = (uint*)d_ws;
    int2* fsorted = (int2*)ws32;
    int2* bsorted = (int2*)(ws32 + 2 * (size_t)E);
    uint* cnt     = ws32 + 4 * (size_t)E;
    uint* tot     = cnt + (size_t)NB * NBLK;
    uint* bbase   = tot + NB;
    uint* nodeoff = bbase + NB + 1;
    float* dv     = (float*)(nodeoff + (size_t)NB * BS + 1);
    float* h      = (float*)bsorted;              // reuse after k_fsort
    float* h1     = h + (size_t)N * 16;

    k_bcount  <<<NBLK, 256, 0, stream>>>(col, cnt, E, NB, chunk);
    k_bprefix <<<NB, 256, 0, stream>>>(cnt, tot);
    k_scanT   <<<1, 256, 0, stream>>>(tot, bbase, NB);
    k_bscatter<<<NBLK, 256, 0, stream>>>(row, col, ew, cnt, bbase, bsorted, E, NB, chunk);
    k_fsort   <<<NB, 256, 0, stream>>>(bsorted, bbase, fsorted, nodeoff, dv, N);
    k_xw1     <<<(N + 63) / 64, 256, 0, stream>>>(x, W1, h, N);
    k_gather_l1   <<<(N + 3) / 4, 256, 0, stream>>>(fsorted, nodeoff, dv, h, b1, h1, N);
    k_gather_l2out<<<(N + 3) / 4, 256, 0, stream>>>(fsorted, nodeoff, dv, h1, W2, b2, out, N);
}